// Round 13
// baseline (1334.217 us; speedup 1.0000x reference)
//
#include <hip/hip_runtime.h>

// RNNSequenceEncoder: B=256, T=256, IN=128, H=1024
// Round-13: XCD-local exchange, third attempt, with a corrected cache model.
// R12 proved sc1 == sc0sc1 (1257us both): all CP traffic costs ~0.9us/leg and
// R10 proved cost ~ CP volume. Escape = keep per-step traffic in the XCD L2.
// R5/R6 deadlocked because sc0 loads are WORKGROUP scope -> they can hit the
// CU's own L1 and poll a stale flag forever. CDNA L1 is WRITE-THROUGH (stores
// always reach the shared XCD L2), so the fix is consumer-side only:
// buffer_inv sc0 (L1-only invalidate; L1 never dirty -> safe) before plain
// reads, which then hit the coherent shared L2.
//   - co-location MEASURED per row-block via HW_REG_XCC_ID (R6 machinery;
//     decision uniform within row-block); LOCAL only if also scratch==d_ws
//   - LOCAL: plain state stores/loads; poll = {inv L1; plain load}; flag
//     published BOTH plain (L2 copy) and sc1 (IF$ backstop)
//   - every 16th poll iteration reads via sc1 (always-correct) -> a wrong
//     model shows as absmax failure or R12-speed, never a hang
//   - fallback path = R12 (sc1) verbatim; epilogue grid barrier always sc1

#define Bdim 256
#define Tdim 256
#define INdim 128
#define Hdim 1024

typedef __attribute__((ext_vector_type(8))) __bf16 bf16x8;
typedef __attribute__((ext_vector_type(4))) float f32x4;
typedef __attribute__((ext_vector_type(4))) int i32x4;

#define OUT_BYTES ((size_t)Bdim * Tdim * Hdim * 4)   /* 256 MB */
#define SBYTES ((size_t)Bdim * Hdim * 2)             /* one bf16 state buffer: 512 KB */
#define CNT_BYTES 32768
#define SCRATCH_BYTES (CNT_BYTES + 2 * SBYTES)

// --- agent-scope ops (bypass L1+L2 to device CP; proven R12) ---
static __device__ __forceinline__ void st_b32_dev(void* p, unsigned v) {
  asm volatile("global_store_dword %0, %1, off sc1" :: "v"(p), "v"(v) : "memory");
}
static __device__ __forceinline__ unsigned ld_b32_dev(const void* p) {
  unsigned v;
  asm volatile("global_load_dword %0, %1, off sc1\n\ts_waitcnt vmcnt(0)"
               : "=v"(v) : "v"(p) : "memory");
  return v;
}
static __device__ __forceinline__ void wait_vm0() {
  asm volatile("s_waitcnt vmcnt(0)" ::: "memory");
}
// L1-only invalidate (L1 is write-through -> never dirty -> pure inv, safe)
static __device__ __forceinline__ void inv_l1() {
  asm volatile("buffer_inv sc0\n\ts_waitcnt vmcnt(0)" ::: "memory");
}
// plain ops (write-through L1 -> shared XCD L2)
static __device__ __forceinline__ void st_b32_l2(void* p, unsigned v) {
  asm volatile("global_store_dword %0, %1, off" :: "v"(p), "v"(v) : "memory");
}
static __device__ __forceinline__ unsigned ld_b32_l2(const void* p) {
  unsigned v;
  asm volatile("global_load_dword %0, %1, off\n\ts_waitcnt vmcnt(0)"
               : "=v"(v) : "v"(p) : "memory");
  return v;
}

// --- templated exchange ops ---
template <bool LOCAL>
static __device__ __forceinline__ void st_state16(void* p, unsigned v) {
  if (LOCAL)
    asm volatile("global_store_short %0, %1, off" :: "v"(p), "v"(v) : "memory");
  else
    asm volatile("global_store_short %0, %1, off sc1" :: "v"(p), "v"(v) : "memory");
}
template <bool LOCAL>
static __device__ __forceinline__ i32x4 ld_state128(const void* p) {
  i32x4 v;
  if (LOCAL)
    asm volatile("global_load_dwordx4 %0, %1, off" : "=v"(v) : "v"(p) : "memory");
  else
    asm volatile("global_load_dwordx4 %0, %1, off sc1" : "=v"(v) : "v"(p) : "memory");
  return v;
}
template <bool LOCAL>
static __device__ __forceinline__ void pub_flag(unsigned* p, unsigned v) {
  if (LOCAL) st_b32_l2(p, v);   // fast local-L2 copy for same-XCD pollers
  st_b32_dev(p, v);             // IF$ backstop (and the only copy if !LOCAL)
}
template <bool LOCAL>
static __device__ __forceinline__ void poll_flag(const unsigned* f, unsigned tgt) {
  if (LOCAL) {
    int it = 0;
    for (;;) {
      inv_l1();                       // kill stale L1 lines (flag AND data)
      if (ld_b32_l2(f) >= tgt) return;
      if ((++it & 15) == 0 && ld_b32_dev(f) >= tgt) return;  // no-hang backstop
      __builtin_amdgcn_s_sleep(1);
    }
  } else {
    while (ld_b32_dev(f) < tgt) __builtin_amdgcn_s_sleep(1);
  }
}

static __device__ __forceinline__ bf16x8 cvt8(f32x4 lo, f32x4 hi) {
  bf16x8 r;
  r[0] = (__bf16)lo[0]; r[1] = (__bf16)lo[1]; r[2] = (__bf16)lo[2]; r[3] = (__bf16)lo[3];
  r[4] = (__bf16)hi[0]; r[5] = (__bf16)hi[1]; r[6] = (__bf16)hi[2]; r[7] = (__bf16)hi[3];
  return r;
}

// Stage 16 rows x 1024 cols bf16 (32KB) -> LDS, XOR swizzle on 16B chunks
// (chunk ch lands at ch ^ (row&7)). 512 threads, 4 pipelined loads, one
// vmcnt(0), then LDS writes. L1 freshness: the preceding poll's inv_l1()
// ran before the barrier, and no stale refill can occur in between.
template <bool LOCAL>
static __device__ __forceinline__ void stage16(const __bf16* __restrict__ src,
                                               __bf16* sA, int tid) {
  int r0 = (tid + 0) >> 7, c0 = (tid + 0) & 127;
  int r1 = (tid + 512) >> 7, c1 = (tid + 512) & 127;
  int r2 = (tid + 1024) >> 7, c2 = (tid + 1024) & 127;
  int r3 = (tid + 1536) >> 7, c3 = (tid + 1536) & 127;
  i32x4 v0 = ld_state128<LOCAL>(src + (size_t)r0 * Hdim + c0 * 8);
  i32x4 v1 = ld_state128<LOCAL>(src + (size_t)r1 * Hdim + c1 * 8);
  i32x4 v2 = ld_state128<LOCAL>(src + (size_t)r2 * Hdim + c2 * 8);
  i32x4 v3 = ld_state128<LOCAL>(src + (size_t)r3 * Hdim + c3 * 8);
  wait_vm0();
  *(i32x4*)(sA + (size_t)r0 * Hdim + ((c0 ^ (r0 & 7)) << 3)) = v0;
  *(i32x4*)(sA + (size_t)r1 * Hdim + ((c1 ^ (r1 & 7)) << 3)) = v1;
  *(i32x4*)(sA + (size_t)r2 * Hdim + ((c2 ^ (r2 & 7)) << 3)) = v2;
  *(i32x4*)(sA + (size_t)r3 * Hdim + ((c3 ^ (r3 & 7)) << 3)) = v3;
}

// A-fragment: lane holds A[row=lane&15][k0..k0+7], k0 = kk*32 + (lane>>4)*8,
// through the same XOR swizzle. A/B use identical K-packing.
static __device__ __forceinline__ bf16x8 afrag(const __bf16* sA, int lane, int kk) {
  int row = lane & 15;
  int ch = kk * 4 + (lane >> 4);
  return *(const bf16x8*)(sA + (size_t)row * Hdim + ((ch ^ (row & 7)) << 3));
}

__global__ void zero_cnt(unsigned* c) { c[blockIdx.x * 256 + threadIdx.x] = 0u; }

template <bool LOCAL>
static __device__ void run_all(const float* __restrict__ x,
                               const float* __restrict__ W_in,
                               const float* __restrict__ b_in,
                               const float* __restrict__ W_rec,
                               const float* __restrict__ b_rec,
                               const float* __restrict__ W_out,
                               const float* __restrict__ b_out,
                               float* __restrict__ out, unsigned* counters,
                               __bf16* buf0, __bf16* buf1, __bf16* sA, int wg,
                               int r, int c, int tid) {
  int lane = tid & 63;
  int ww = tid >> 6;
  int kgrp = lane >> 4;
  int col = c * 128 + ww * 16 + (lane & 15);

  unsigned* rbf = counters + (size_t)r * 8 * 32;   // row-block flags, 128B apart
  unsigned* myflag = rbf + (size_t)c * 32;
  unsigned* gflags = counters + 4096;              // epilogue one-shot flags

  // --- preload weights (normal cached loads) ---
  bf16x8 wrec[32];  // W_rec row `col`, K=1024 -> 128 VGPRs
#pragma unroll
  for (int kk = 0; kk < 32; ++kk) {
    const float* p = W_rec + (size_t)col * Hdim + kk * 32 + kgrp * 8;
    wrec[kk] = cvt8(*(const f32x4*)p, *(const f32x4*)(p + 4));
  }
  bf16x8 win[4];    // W_in row `col`, K=128
#pragma unroll
  for (int kk = 0; kk < 4; ++kk) {
    const float* p = W_in + (size_t)col * INdim + kk * 32 + kgrp * 8;
    win[kk] = cvt8(*(const f32x4*)p, *(const f32x4*)(p + 4));
  }
  float b_rec_l = b_rec[col];
  float b_in_l = b_in[col];

  int xrow = 16 * r + (lane & 15);
  int xk0 = kgrp * 8;

  // --- phase 0: buf0 = version 1 = ext_0 ---
  {
    f32x4 e = {0.f, 0.f, 0.f, 0.f};
#pragma unroll
    for (int kk = 0; kk < 4; ++kk) {
      const float* p = x + ((size_t)xrow * Tdim + 0) * INdim + kk * 32 + xk0;
      e = __builtin_amdgcn_mfma_f32_16x16x32_bf16(
          cvt8(*(const f32x4*)p, *(const f32x4*)(p + 4)), win[kk], e, 0, 0, 0);
    }
#pragma unroll
    for (int j = 0; j < 4; ++j) {
      __bf16 b = (__bf16)(e[j] + b_in_l);
      st_state16<LOCAL>(buf0 + (size_t)(16 * r + kgrp * 4 + j) * Hdim + col,
                        (unsigned)__builtin_bit_cast(unsigned short, b));
    }
  }
  wait_vm0();
  __syncthreads();
  if (tid == 0) pub_flag<LOCAL>(myflag, 1u);
  if (tid < 8) poll_flag<LOCAL>(rbf + tid * 32, 1u);
  __syncthreads();

  // --- scan: 256 steps; version t+1 in buf[t&1] ---
  const __bf16* cur = buf0;
  __bf16* nxt = buf1;
  for (int t = 0; t < Tdim; ++t) {
    stage16<LOCAL>(cur + (size_t)r * 16 * Hdim, sA, tid);
    f32x4 xlo[4], xhi[4];
    if (t + 1 < Tdim) {
#pragma unroll
      for (int kk = 0; kk < 4; ++kk) {
        const float* p = x + ((size_t)xrow * Tdim + (t + 1)) * INdim + kk * 32 + xk0;
        xlo[kk] = *(const f32x4*)p;
        xhi[kk] = *(const f32x4*)(p + 4);
      }
    }
    __syncthreads();
    f32x4 a0 = {0.f, 0.f, 0.f, 0.f}, a1 = a0, a2 = a0, a3 = a0;
#pragma unroll
    for (int kk = 0; kk < 32; kk += 4) {
      a0 = __builtin_amdgcn_mfma_f32_16x16x32_bf16(afrag(sA, lane, kk + 0), wrec[kk + 0], a0, 0, 0, 0);
      a1 = __builtin_amdgcn_mfma_f32_16x16x32_bf16(afrag(sA, lane, kk + 1), wrec[kk + 1], a1, 0, 0, 0);
      a2 = __builtin_amdgcn_mfma_f32_16x16x32_bf16(afrag(sA, lane, kk + 2), wrec[kk + 2], a2, 0, 0, 0);
      a3 = __builtin_amdgcn_mfma_f32_16x16x32_bf16(afrag(sA, lane, kk + 3), wrec[kk + 3], a3, 0, 0, 0);
    }
    f32x4 acc = (a0 + a1) + (a2 + a3);
    f32x4 e = {0.f, 0.f, 0.f, 0.f};
    if (t + 1 < Tdim) {
#pragma unroll
      for (int kk = 0; kk < 4; ++kk)
        e = __builtin_amdgcn_mfma_f32_16x16x32_bf16(cvt8(xlo[kk], xhi[kk]), win[kk], e, 0, 0, 0);
    }
    // C/D layout: col = lane&15, row = (lane>>4)*4 + j
#pragma unroll
    for (int j = 0; j < 4; ++j) {
      float s = acc[j] + b_rec_l;
      s = s > 0.f ? s : 0.f;
      float v = (t + 1 < Tdim) ? (s + e[j] + b_in_l) : s;
      __bf16 b = (__bf16)v;
      st_state16<LOCAL>(nxt + (size_t)(16 * r + kgrp * 4 + j) * Hdim + col,
                        (unsigned)__builtin_bit_cast(unsigned short, b));
    }
    // publish v(t+2): own stores ack'd (write-through L1 -> L2) -> barrier ->
    // flag -> poll peers >= t+2 (also proves nobody still reads v(t+1)).
    unsigned tgt = (unsigned)(t + 2);
    wait_vm0();
    __syncthreads();
    if (tid == 0) pub_flag<LOCAL>(myflag, tgt);
    if (tid < 8) poll_flag<LOCAL>(rbf + tid * 32, tgt);
    __syncthreads();
    const __bf16* tmp = cur; cur = nxt; nxt = (__bf16*)tmp;
  }

  // --- output: plop = state_257 @ W_out^T + b_out, broadcast over T ---
  stage16<LOCAL>(buf0 + (size_t)r * 16 * Hdim, sA, tid);
  __syncthreads();
  // one-shot grid barrier: always device-scope (cross-XCD; tail-scratch safety)
  if (tid == 0) st_b32_dev(gflags + (size_t)wg * 16, 1u);
  if (tid < 128) {
    unsigned* f = gflags + (size_t)tid * 16;
    while (ld_b32_dev(f) < 1u) __builtin_amdgcn_s_sleep(1);
  }
  __syncthreads();

  f32x4 a0 = {0.f, 0.f, 0.f, 0.f}, a1 = a0;
#pragma unroll
  for (int kk = 0; kk < 32; kk += 2) {
    const float* p0 = W_out + (size_t)col * Hdim + (kk + 0) * 32 + kgrp * 8;
    const float* p1 = W_out + (size_t)col * Hdim + (kk + 1) * 32 + kgrp * 8;
    a0 = __builtin_amdgcn_mfma_f32_16x16x32_bf16(
        afrag(sA, lane, kk + 0), cvt8(*(const f32x4*)p0, *(const f32x4*)(p0 + 4)), a0, 0, 0, 0);
    a1 = __builtin_amdgcn_mfma_f32_16x16x32_bf16(
        afrag(sA, lane, kk + 1), cvt8(*(const f32x4*)p1, *(const f32x4*)(p1 + 4)), a1, 0, 0, 0);
  }
  f32x4 acc = a0 + a1;
  float bo = b_out[col];
  __syncthreads();  // afrag reads done before sA reuse
  float* sP = (float*)sA;  // 16 x 128 plop tile (f32, 8KB)
#pragma unroll
  for (int j = 0; j < 4; ++j)
    sP[(kgrp * 4 + j) * 128 + ww * 16 + (lane & 15)] = acc[j] + bo;
  __syncthreads();

  int h32 = tid & 31, tloc = tid >> 5;
  for (int b = 0; b < 16; ++b) {
    f32x4 v = *(const f32x4*)(sP + b * 128 + h32 * 4);
#pragma unroll
    for (int tb = 0; tb < 16; ++tb) {
      int t = tb * 16 + tloc;
      *(f32x4*)(out + ((size_t)(16 * r + b) * Tdim + t) * Hdim + 128 * c + h32 * 4) = v;
    }
  }
}

__global__ void __launch_bounds__(512, 1)
rnn_fused(const float* __restrict__ x, const float* __restrict__ W_in,
          const float* __restrict__ b_in, const float* __restrict__ W_rec,
          const float* __restrict__ b_rec, const float* __restrict__ W_out,
          const float* __restrict__ b_out, float* __restrict__ out,
          char* __restrict__ scratch, int ws_ok) {
  __shared__ __align__(16) __bf16 sA[16 * Hdim];  // 32 KB
  __shared__ int sX[8];

  unsigned* counters = (unsigned*)scratch;
  __bf16* buf0 = (__bf16*)(scratch + CNT_BYTES);
  __bf16* buf1 = buf0 + (size_t)Bdim * Hdim;

  int wg = blockIdx.x;               // 0..127
  int idx = wg >> 3;
  int r = (wg & 7) + 8 * (idx & 1);  // row block 0..15; its 8 WGs share wg&7
  int c = idx >> 1;                  // col chunk 0..7 (128 H cols)
  int tid = threadIdx.x;

  // --- startup: measure XCC_ID; row-block r goes XCD-local iff all 8 of its
  // member WGs sit on the SAME XCC (measured) and scratch is in d_ws.
  // Decision uniform within the row-block. Publication device-scope (proven).
  int my_xcc = 0;
  asm volatile("s_getreg_b32 %0, hwreg(HW_REG_XCC_ID)" : "=s"(my_xcc));
  unsigned* xtab = counters + 6144;  // 128 slots, 64B apart
  if (tid == 0) st_b32_dev(xtab + (size_t)wg * 16, (unsigned)(my_xcc + 1));
  if (tid < 8) {
    int wgm = (r & 7) + 8 * ((r >> 3) + 2 * tid);  // row-block member WGs
    unsigned v;
    unsigned* f = xtab + (size_t)wgm * 16;
    while ((v = ld_b32_dev(f)) == 0u) __builtin_amdgcn_s_sleep(1);
    sX[tid] = (int)v;
  }
  __syncthreads();
  int allc = 1;
  for (int i = 0; i < 8; ++i) allc &= (sX[i] == sX[0]);

  if (allc && ws_ok)
    run_all<true>(x, W_in, b_in, W_rec, b_rec, W_out, b_out, out, counters,
                  buf0, buf1, sA, wg, r, c, tid);
  else
    run_all<false>(x, W_in, b_in, W_rec, b_rec, W_out, b_out, out, counters,
                   buf0, buf1, sA, wg, r, c, tid);
}

extern "C" void kernel_launch(void* const* d_in, const int* in_sizes, int n_in,
                              void* d_out, int out_size, void* d_ws, size_t ws_size,
                              hipStream_t stream) {
  const float* x = (const float*)d_in[0];
  const float* W_in = (const float*)d_in[1];
  const float* b_in = (const float*)d_in[2];
  const float* W_rec = (const float*)d_in[3];
  const float* b_rec = (const float*)d_in[4];
  const float* W_out = (const float*)d_in[5];
  const float* b_out = (const float*)d_in[6];
  float* out = (float*)d_out;
  (void)in_sizes; (void)n_in; (void)out_size;

  int ws_ok = (ws_size >= SCRATCH_BYTES) ? 1 : 0;
  char* scratch = ws_ok ? (char*)d_ws
                        : ((char*)d_out + OUT_BYTES - SCRATCH_BYTES);

  zero_cnt<<<dim3(CNT_BYTES / 1024), dim3(256), 0, stream>>>((unsigned*)scratch);
  rnn_fused<<<dim3(128), dim3(512), 0, stream>>>(x, W_in, b_in, W_rec, b_rec,
                                                 W_out, b_out, out, scratch, ws_ok);
}

// Round 14
// 973.328 us; speedup vs baseline: 1.3708x; 1.3708x over previous
//
#include <hip/hip_runtime.h>

// RNNSequenceEncoder: B=256, T=256, IN=128, H=1024
// Round-14: R13 proved XCD-local exchange is CORRECT and kills HBM traffic
// (FETCH 127->61MB, WRITE 407->279MB) but time stayed ~1300us. Residues:
// (a) R13 paid buffer_inv+vmcnt on EVERY poll iteration; (b) compute phase
// is LDS-port-bound: 8 waves x 32KB ds_read = 256KB/CU/step (~1.2us).
// Fixes, data-path only (protocol = proven R4/R12 shape):
//  (1) poll flags via sc1 (R4/R12-proven), then ONE buffer_inv sc0 by wave 0
//      before the barrier; all waves' plain stage loads then hit fresh L2.
//      (R13 already proved one CU-wide inv covers all waves' loads.)
//  (2) 256-thread WGs: 4 waves x 32 cols (wrec 64 frags = 256 VGPRs); each
//      afrag LDS read feeds TWO MFMAs -> LDS reads halve to 128KB/CU/step.
//  (3) LOCAL state stores plain (write-through -> XCD L2, fast ack);
//      fallback path = R12 (sc1) for non-colocated row-blocks / tail-scratch.

#define Bdim 256
#define Tdim 256
#define INdim 128
#define Hdim 1024

typedef __attribute__((ext_vector_type(8))) __bf16 bf16x8;
typedef __attribute__((ext_vector_type(4))) float f32x4;
typedef __attribute__((ext_vector_type(4))) int i32x4;

#define OUT_BYTES ((size_t)Bdim * Tdim * Hdim * 4)   /* 256 MB */
#define SBYTES ((size_t)Bdim * Hdim * 2)             /* one bf16 state buffer: 512 KB */
#define CNT_BYTES 32768
#define SCRATCH_BYTES (CNT_BYTES + 2 * SBYTES)

// --- agent-scope ops (bypass L1+L2 to device CP; proven R12) ---
static __device__ __forceinline__ void st_b32_dev(void* p, unsigned v) {
  asm volatile("global_store_dword %0, %1, off sc1" :: "v"(p), "v"(v) : "memory");
}
static __device__ __forceinline__ unsigned ld_b32_dev(const void* p) {
  unsigned v;
  asm volatile("global_load_dword %0, %1, off sc1\n\ts_waitcnt vmcnt(0)"
               : "=v"(v) : "v"(p) : "memory");
  return v;
}
static __device__ __forceinline__ void wait_vm0() {
  asm volatile("s_waitcnt vmcnt(0)" ::: "memory");
}
// L1-only invalidate (write-through L1 is never dirty -> pure inv; proven R13)
static __device__ __forceinline__ void inv_l1() {
  asm volatile("buffer_inv sc0\n\ts_waitcnt vmcnt(0)" ::: "memory");
}

// --- templated state ops: LOCAL -> plain (write-through L1 -> shared XCD L2);
//     else sc1 (device CP). ---
template <bool LOCAL>
static __device__ __forceinline__ void st_state16(void* p, unsigned v) {
  if (LOCAL)
    asm volatile("global_store_short %0, %1, off" :: "v"(p), "v"(v) : "memory");
  else
    asm volatile("global_store_short %0, %1, off sc1" :: "v"(p), "v"(v) : "memory");
}
template <bool LOCAL>
static __device__ __forceinline__ i32x4 ld_state128(const void* p) {
  i32x4 v;
  if (LOCAL)
    asm volatile("global_load_dwordx4 %0, %1, off" : "=v"(v) : "v"(p) : "memory");
  else
    asm volatile("global_load_dwordx4 %0, %1, off sc1" : "=v"(v) : "v"(p) : "memory");
  return v;
}

static __device__ __forceinline__ bf16x8 cvt8(f32x4 lo, f32x4 hi) {
  bf16x8 r;
  r[0] = (__bf16)lo[0]; r[1] = (__bf16)lo[1]; r[2] = (__bf16)lo[2]; r[3] = (__bf16)lo[3];
  r[4] = (__bf16)hi[0]; r[5] = (__bf16)hi[1]; r[6] = (__bf16)hi[2]; r[7] = (__bf16)hi[3];
  return r;
}
static __device__ __forceinline__ unsigned short bfbits(float f) {
  __bf16 b = (__bf16)f;
  return __builtin_bit_cast(unsigned short, b);
}

// A-fragment: lane holds A[row=lane&15][k0..k0+7], k0 = kk*32 + (lane>>4)*8,
// through the XOR swizzle (16B chunk ch at ch ^ (row&7)). A/B use identical
// K-packing so any HW K-permutation cancels. (Proven rounds 2-13.)
static __device__ __forceinline__ bf16x8 afrag(const __bf16* sA, int lane, int kk) {
  int row = lane & 15;
  int ch = kk * 4 + (lane >> 4);
  return *(const bf16x8*)(sA + (size_t)row * Hdim + ((ch ^ (row & 7)) << 3));
}

// Stage 16 rows x 1024 cols bf16 (32KB) -> LDS with the XOR swizzle.
// 256 threads x 8 chunks of 16B; all loads issued, one vmcnt, LDS writes.
template <bool LOCAL>
static __device__ __forceinline__ void stage16(const __bf16* __restrict__ src,
                                               __bf16* sA, int tid) {
  i32x4 d[8];
  int rw[8], chv[8];
#pragma unroll
  for (int q = 0; q < 8; ++q) {
    int slot = q * 256 + tid;
    rw[q] = slot >> 7;
    chv[q] = slot & 127;
    d[q] = ld_state128<LOCAL>(src + (size_t)rw[q] * Hdim + chv[q] * 8);
  }
  wait_vm0();
#pragma unroll
  for (int q = 0; q < 8; ++q)
    *(i32x4*)(sA + (size_t)rw[q] * Hdim + ((chv[q] ^ (rw[q] & 7)) << 3)) = d[q];
}

__global__ void zero_cnt(unsigned* c) { c[blockIdx.x * 256 + threadIdx.x] = 0u; }

template <bool LOCAL>
static __device__ void run_all(const float* __restrict__ x,
                               const float* __restrict__ W_in,
                               const float* __restrict__ b_in,
                               const float* __restrict__ W_rec,
                               const float* __restrict__ b_rec,
                               const float* __restrict__ W_out,
                               const float* __restrict__ b_out,
                               float* __restrict__ out, unsigned* counters,
                               __bf16* buf0, __bf16* buf1, __bf16* sA, int wg,
                               int r, int c, int tid) {
  int lane = tid & 63;
  int ww = tid >> 6;                 // wave 0..3, 32 cols each
  int kgrp = lane >> 4;
  int n16 = lane & 15;
  int col0 = c * 128 + ww * 32 + n16;   // col-tile 0
  int col1 = col0 + 16;                 // col-tile 1

  unsigned* rbf = counters + (size_t)r * 8 * 32;   // row-block flags, 128B apart
  unsigned* myflag = rbf + (size_t)c * 32;
  unsigned* gflags = counters + 4096;              // epilogue one-shot flags

  // --- preload weights (normal cached loads): 2 col-tiles x 32 K-frags ---
  bf16x8 wrec0[32], wrec1[32];  // 256 VGPRs
#pragma unroll
  for (int kk = 0; kk < 32; ++kk) {
    const float* p0 = W_rec + (size_t)col0 * Hdim + kk * 32 + kgrp * 8;
    const float* p1 = W_rec + (size_t)col1 * Hdim + kk * 32 + kgrp * 8;
    wrec0[kk] = cvt8(*(const f32x4*)p0, *(const f32x4*)(p0 + 4));
    wrec1[kk] = cvt8(*(const f32x4*)p1, *(const f32x4*)(p1 + 4));
  }
  bf16x8 win0[4], win1[4];
#pragma unroll
  for (int kk = 0; kk < 4; ++kk) {
    const float* p0 = W_in + (size_t)col0 * INdim + kk * 32 + kgrp * 8;
    const float* p1 = W_in + (size_t)col1 * INdim + kk * 32 + kgrp * 8;
    win0[kk] = cvt8(*(const f32x4*)p0, *(const f32x4*)(p0 + 4));
    win1[kk] = cvt8(*(const f32x4*)p1, *(const f32x4*)(p1 + 4));
  }
  float brec0 = b_rec[col0], brec1 = b_rec[col1];
  float bin0 = b_in[col0], bin1 = b_in[col1];

  int xrow = 16 * r + n16;
  int xk0 = kgrp * 8;

  // --- phase 0: buf0 = version 1 = ext_0 ---
  {
    f32x4 e0 = {0.f, 0.f, 0.f, 0.f}, e1 = e0;
#pragma unroll
    for (int kk = 0; kk < 4; ++kk) {
      const float* p = x + ((size_t)xrow * Tdim + 0) * INdim + kk * 32 + xk0;
      bf16x8 xf = cvt8(*(const f32x4*)p, *(const f32x4*)(p + 4));
      e0 = __builtin_amdgcn_mfma_f32_16x16x32_bf16(xf, win0[kk], e0, 0, 0, 0);
      e1 = __builtin_amdgcn_mfma_f32_16x16x32_bf16(xf, win1[kk], e1, 0, 0, 0);
    }
#pragma unroll
    for (int j = 0; j < 4; ++j) {
      st_state16<LOCAL>(buf0 + (size_t)(16 * r + kgrp * 4 + j) * Hdim + col0,
                        (unsigned)bfbits(e0[j] + bin0));
      st_state16<LOCAL>(buf0 + (size_t)(16 * r + kgrp * 4 + j) * Hdim + col1,
                        (unsigned)bfbits(e1[j] + bin1));
    }
  }
  wait_vm0();
  __syncthreads();
  if (tid == 0) st_b32_dev(myflag, 1u);
  if (tid < 8) {
    unsigned* f = rbf + tid * 32;
    while (ld_b32_dev(f) < 1u) __builtin_amdgcn_s_sleep(1);
  }
  if (LOCAL && tid < 64) inv_l1();   // one CU-wide L1 inv; covers all waves
  __syncthreads();

  // --- scan: 256 steps; version t+1 in buf[t&1] ---
  const __bf16* cur = buf0;
  __bf16* nxt = buf1;
  for (int t = 0; t < Tdim; ++t) {
    stage16<LOCAL>(cur + (size_t)r * 16 * Hdim, sA, tid);
    f32x4 xlo[4], xhi[4];
    if (t + 1 < Tdim) {
#pragma unroll
      for (int kk = 0; kk < 4; ++kk) {
        const float* p = x + ((size_t)xrow * Tdim + (t + 1)) * INdim + kk * 32 + xk0;
        xlo[kk] = *(const f32x4*)p;
        xhi[kk] = *(const f32x4*)(p + 4);
      }
    }
    __syncthreads();
    // one afrag LDS read feeds BOTH col-tiles' MFMAs (halves LDS traffic)
    f32x4 a00 = {0.f, 0.f, 0.f, 0.f}, a01 = a00, a10 = a00, a11 = a00;
#pragma unroll
    for (int kk = 0; kk < 32; kk += 2) {
      bf16x8 s0 = afrag(sA, lane, kk + 0);
      bf16x8 s1 = afrag(sA, lane, kk + 1);
      a00 = __builtin_amdgcn_mfma_f32_16x16x32_bf16(s0, wrec0[kk + 0], a00, 0, 0, 0);
      a01 = __builtin_amdgcn_mfma_f32_16x16x32_bf16(s0, wrec1[kk + 0], a01, 0, 0, 0);
      a10 = __builtin_amdgcn_mfma_f32_16x16x32_bf16(s1, wrec0[kk + 1], a10, 0, 0, 0);
      a11 = __builtin_amdgcn_mfma_f32_16x16x32_bf16(s1, wrec1[kk + 1], a11, 0, 0, 0);
    }
    f32x4 acc0 = a00 + a10, acc1 = a01 + a11;
    f32x4 e0 = {0.f, 0.f, 0.f, 0.f}, e1 = e0;
    if (t + 1 < Tdim) {
#pragma unroll
      for (int kk = 0; kk < 4; ++kk) {
        bf16x8 xf = cvt8(xlo[kk], xhi[kk]);
        e0 = __builtin_amdgcn_mfma_f32_16x16x32_bf16(xf, win0[kk], e0, 0, 0, 0);
        e1 = __builtin_amdgcn_mfma_f32_16x16x32_bf16(xf, win1[kk], e1, 0, 0, 0);
      }
    }
    // C/D layout: col = lane&15 (per tile), row = kgrp*4 + j
#pragma unroll
    for (int j = 0; j < 4; ++j) {
      float s0 = acc0[j] + brec0, s1 = acc1[j] + brec1;
      s0 = s0 > 0.f ? s0 : 0.f; s1 = s1 > 0.f ? s1 : 0.f;
      if (t + 1 < Tdim) { s0 += e0[j] + bin0; s1 += e1[j] + bin1; }
      st_state16<LOCAL>(nxt + (size_t)(16 * r + kgrp * 4 + j) * Hdim + col0,
                        (unsigned)bfbits(s0));
      st_state16<LOCAL>(nxt + (size_t)(16 * r + kgrp * 4 + j) * Hdim + col1,
                        (unsigned)bfbits(s1));
    }
    // publish v(t+2): own stores ack'd -> barrier -> flag -> poll peers.
    // Poll exit >= t+2 proves nobody still reads v(t+1) (2-buffer safe).
    unsigned tgt = (unsigned)(t + 2);
    wait_vm0();
    __syncthreads();
    if (tid == 0) st_b32_dev(myflag, tgt);
    if (tid < 8) {
      unsigned* f = rbf + tid * 32;
      while (ld_b32_dev(f) < tgt) __builtin_amdgcn_s_sleep(1);
    }
    if (LOCAL && tid < 64) inv_l1();   // ONE inv/step, after poll, pre-barrier
    __syncthreads();
    const __bf16* tmp = cur; cur = nxt; nxt = (__bf16*)tmp;
  }

  // --- output: plop = state_257 @ W_out^T + b_out, broadcast over T ---
  stage16<LOCAL>(buf0 + (size_t)r * 16 * Hdim, sA, tid);
  __syncthreads();
  // one-shot grid barrier: device scope (cross-XCD; tail-scratch safety)
  if (tid == 0) st_b32_dev(gflags + (size_t)wg * 16, 1u);
  if (tid < 128) {
    unsigned* f = gflags + (size_t)tid * 16;
    while (ld_b32_dev(f) < 1u) __builtin_amdgcn_s_sleep(1);
  }
  __syncthreads();

  f32x4 a0 = {0.f, 0.f, 0.f, 0.f}, a1 = a0;
#pragma unroll
  for (int kk = 0; kk < 32; ++kk) {
    const float* p0 = W_out + (size_t)col0 * Hdim + kk * 32 + kgrp * 8;
    const float* p1 = W_out + (size_t)col1 * Hdim + kk * 32 + kgrp * 8;
    bf16x8 s0 = afrag(sA, lane, kk);
    a0 = __builtin_amdgcn_mfma_f32_16x16x32_bf16(
        s0, cvt8(*(const f32x4*)p0, *(const f32x4*)(p0 + 4)), a0, 0, 0, 0);
    a1 = __builtin_amdgcn_mfma_f32_16x16x32_bf16(
        s0, cvt8(*(const f32x4*)p1, *(const f32x4*)(p1 + 4)), a1, 0, 0, 0);
  }
  float bo0 = b_out[col0], bo1 = b_out[col1];
  __syncthreads();  // afrag reads done before sA reuse
  float* sP = (float*)sA;  // 16 x 128 plop tile (f32, 8KB), [batch row][col]
#pragma unroll
  for (int j = 0; j < 4; ++j) {
    sP[(kgrp * 4 + j) * 128 + ww * 32 + n16] = a0[j] + bo0;
    sP[(kgrp * 4 + j) * 128 + ww * 32 + 16 + n16] = a1[j] + bo1;
  }
  __syncthreads();

  int h32 = tid & 31, tloc = tid >> 5;  // 32 f32x4-cols, 8 t-phases
  for (int b = 0; b < 16; ++b) {
    f32x4 v = *(const f32x4*)(sP + b * 128 + h32 * 4);
#pragma unroll
    for (int tb = 0; tb < 32; ++tb) {
      int t = tb * 8 + tloc;
      *(f32x4*)(out + ((size_t)(16 * r + b) * Tdim + t) * Hdim + 128 * c + h32 * 4) = v;
    }
  }
}

__global__ void __launch_bounds__(256, 1)
rnn_fused(const float* __restrict__ x, const float* __restrict__ W_in,
          const float* __restrict__ b_in, const float* __restrict__ W_rec,
          const float* __restrict__ b_rec, const float* __restrict__ W_out,
          const float* __restrict__ b_out, float* __restrict__ out,
          char* __restrict__ scratch, int ws_ok) {
  __shared__ __align__(16) __bf16 sA[16 * Hdim];  // 32 KB
  __shared__ int sX[8];

  unsigned* counters = (unsigned*)scratch;
  __bf16* buf0 = (__bf16*)(scratch + CNT_BYTES);
  __bf16* buf1 = buf0 + (size_t)Bdim * Hdim;

  int wg = blockIdx.x;               // 0..127
  int idx = wg >> 3;
  int r = (wg & 7) + 8 * (idx & 1);  // row block 0..15; its 8 WGs share wg&7
  int c = idx >> 1;                  // col chunk 0..7 (128 H cols)
  int tid = threadIdx.x;

  // startup: measure XCC_ID; row-block goes LOCAL iff its 8 member WGs share
  // one XCC (measured; uniform decision) and scratch is in d_ws. (R6/R13.)
  int my_xcc = 0;
  asm volatile("s_getreg_b32 %0, hwreg(HW_REG_XCC_ID)" : "=s"(my_xcc));
  unsigned* xtab = counters + 6144;  // 128 slots, 64B apart
  if (tid == 0) st_b32_dev(xtab + (size_t)wg * 16, (unsigned)(my_xcc + 1));
  if (tid < 8) {
    int wgm = (r & 7) + 8 * ((r >> 3) + 2 * tid);  // row-block member WGs
    unsigned v;
    unsigned* f = xtab + (size_t)wgm * 16;
    while ((v = ld_b32_dev(f)) == 0u) __builtin_amdgcn_s_sleep(1);
    sX[tid] = (int)v;
  }
  __syncthreads();
  int allc = 1;
  for (int i = 0; i < 8; ++i) allc &= (sX[i] == sX[0]);

  if (allc && ws_ok)
    run_all<true>(x, W_in, b_in, W_rec, b_rec, W_out, b_out, out, counters,
                  buf0, buf1, sA, wg, r, c, tid);
  else
    run_all<false>(x, W_in, b_in, W_rec, b_rec, W_out, b_out, out, counters,
                   buf0, buf1, sA, wg, r, c, tid);
}

extern "C" void kernel_launch(void* const* d_in, const int* in_sizes, int n_in,
                              void* d_out, int out_size, void* d_ws, size_t ws_size,
                              hipStream_t stream) {
  const float* x = (const float*)d_in[0];
  const float* W_in = (const float*)d_in[1];
  const float* b_in = (const float*)d_in[2];
  const float* W_rec = (const float*)d_in[3];
  const float* b_rec = (const float*)d_in[4];
  const float* W_out = (const float*)d_in[5];
  const float* b_out = (const float*)d_in[6];
  float* out = (float*)d_out;
  (void)in_sizes; (void)n_in; (void)out_size;

  int ws_ok = (ws_size >= SCRATCH_BYTES) ? 1 : 0;
  char* scratch = ws_ok ? (char*)d_ws
                        : ((char*)d_out + OUT_BYTES - SCRATCH_BYTES);

  zero_cnt<<<dim3(CNT_BYTES / 1024), dim3(256), 0, stream>>>((unsigned*)scratch);
  rnn_fused<<<dim3(128), dim3(256), 0, stream>>>(x, W_in, b_in, W_rec, b_rec,
                                                 W_out, b_out, out, scratch, ws_ok);
}